// Round 4
// baseline (976.167 us; speedup 1.0000x reference)
//
#include <hip/hip_runtime.h>

#define LOG2E 1.4426950408889634f
#define ATTN_SCALE 0.08838834764831843f   // 1/sqrt(128)

using bhalf8 = __attribute__((ext_vector_type(8))) short;  // 8 bf16 in 4 VGPRs
using f32x4  = __attribute__((ext_vector_type(4))) float;  // MFMA accumulator

// round-to-nearest-even fp32 -> bf16
__device__ __forceinline__ unsigned short f2bf(float f) {
  unsigned u = __float_as_uint(f);
  u += 0x7fffu + ((u >> 16) & 1u);
  return (unsigned short)(u >> 16);
}

// pack two fp32 -> bf16x2 (round-half-up) with one v_perm_b32
__device__ __forceinline__ unsigned pack_bf16_2(float lo, float hi) {
  unsigned a = __float_as_uint(lo) + 0x8000u;
  unsigned b = __float_as_uint(hi) + 0x8000u;
  return __builtin_amdgcn_perm(b, a, 0x07060302);  // D = {b.hi16, a.hi16}
}

// async global->LDS DMA, 16B per lane; lds dest must be wave-uniform base
__device__ __forceinline__ void gl_lds16(const unsigned short* g, unsigned short* l) {
  __builtin_amdgcn_global_load_lds(
      (const __attribute__((address_space(1))) void*)g,
      (__attribute__((address_space(3))) void*)l, 16, 0, 0);
}

// ---------------- fp32 -> bf16 convert, 4 elems/thread ----------------
__global__ void cvt_kernel(const float* __restrict__ src,
                           unsigned short* __restrict__ dst, int n4) {
  int i = blockIdx.x * blockDim.x + threadIdx.x;
  if (i >= n4) return;
  float4 f = reinterpret_cast<const float4*>(src)[i];
  unsigned lo = (unsigned)f2bf(f.x) | ((unsigned)f2bf(f.y) << 16);
  unsigned hi = (unsigned)f2bf(f.z) | ((unsigned)f2bf(f.w) << 16);
  reinterpret_cast<uint2*>(dst)[i] = make_uint2(lo, hi);
}

// =====================================================================
// 256x256-tile 8-phase GEMM (T2+T3+T4+T5 stack), C = A[M,2048] * Bt[N,2048]^T
// 512 threads (8 waves, 2Mx4N), BK=64, 128 KiB LDS double-buffer.
// Block->tile mapping is XCD-aware (T1): with XCD = linear_wgid % 8, XCD k
// owns rows 4k..4k+3 x all 8 cols -> per-XCD working set 12 MB not 33 MB.
// MFMA inner order: kk OUTERMOST so dependent writes to the same acc are
// spaced by 8 independent MFMAs (dependent back-to-back stalls the pipe).
// MODE 0: bf16 out, split heads [b,h,s,d]   (Q, K projections)
// MODE 1: bf16 out, transposed [b,h,d,s]    (V projection; MFMA swapped)
// MODE 2: fp32 out + bias, row-major [M,N]  (output projection)
// =====================================================================
#define GBAR()  asm volatile("s_barrier" ::: "memory")
#define GWAITL() do { asm volatile("s_waitcnt lgkmcnt(0)" ::: "memory"); \
                      __builtin_amdgcn_sched_barrier(0); } while (0)

__device__ __forceinline__ bhalf8 ldsfrag(const unsigned short* b, int rb, int kk,
                                          int rbase) {
  return *reinterpret_cast<const bhalf8*>(b + rb * 1024 + kk * 512 + rbase);
}

template <int MODE, int I0, int J0>
__device__ __forceinline__ void mfmaq(f32x4 (&acc)[8][4], const bhalf8 (&afr)[4][2],
                                      const bhalf8 (&bfr)[2][2]) {
#pragma unroll
  for (int kk = 0; kk < 2; ++kk)
#pragma unroll
    for (int i = 0; i < 4; ++i)
#pragma unroll
      for (int j = 0; j < 2; ++j) {
        if (MODE == 1)
          acc[I0 + i][J0 + j] = __builtin_amdgcn_mfma_f32_16x16x32_bf16(
              bfr[j][kk], afr[i][kk], acc[I0 + i][J0 + j], 0, 0, 0);
        else
          acc[I0 + i][J0 + j] = __builtin_amdgcn_mfma_f32_16x16x32_bf16(
              afr[i][kk], bfr[j][kk], acc[I0 + i][J0 + j], 0, 0, 0);
      }
}

// stage one half-tile (128 rows x 64 k) : 2 x global_load_lds per thread.
// rdec/cdec: per-thread (row, swizzled-k) decode of the linear LDS chunk.
__device__ __forceinline__ void stage_half(const unsigned short* __restrict__ M,
                                           unsigned short* dstbase, int h, int ks,
                                           int rowb, int wave, const int (&rdec)[2],
                                           const int (&cdec)[2]) {
#pragma unroll
  for (int ld = 0; ld < 2; ++ld)
    gl_lds16(M + (size_t)(rowb + rdec[ld] + h * 128) * 2048 + ks + cdec[ld],
             dstbase + h * 8192 + ld * 4096 + wave * 512);
}

template <int MODE>
__device__ __forceinline__ void ktile256(
    const unsigned short* __restrict__ A, const unsigned short* __restrict__ Bt,
    unsigned short* as_, unsigned short* bs_, int ks,
    int row0, int col0, int wave, int wr, int wc, int rbase,
    const int (&rdec)[2], const int (&cdec)[2],
    f32x4 (&acc)[8][4], bhalf8 (&af)[4][2], bhalf8 (&bfA)[2][2], bhalf8 (&bfB)[2][2]) {
  // ---- phase 0: read A rows [wr*128, +64) + B rows [wc*64, +32); MFMA Q(0,0)
#pragma unroll
  for (int i = 0; i < 4; ++i)
#pragma unroll
    for (int kk = 0; kk < 2; ++kk) af[i][kk] = ldsfrag(as_, wr * 8 + i, kk, rbase);
#pragma unroll
  for (int j = 0; j < 2; ++j)
#pragma unroll
    for (int kk = 0; kk < 2; ++kk) bfA[j][kk] = ldsfrag(bs_, wc * 4 + j, kk, rbase);
  GBAR(); GWAITL();
  __builtin_amdgcn_s_setprio(1);
  mfmaq<MODE, 0, 0>(acc, af, bfA);
  __builtin_amdgcn_s_setprio(0);
  GBAR();
  // ---- phase 1: read B rows [wc*64+32, +32); MFMA Q(0,2).  B fully read after this.
#pragma unroll
  for (int j = 0; j < 2; ++j)
#pragma unroll
    for (int kk = 0; kk < 2; ++kk) bfB[j][kk] = ldsfrag(bs_, wc * 4 + 2 + j, kk, rbase);
  GBAR(); GWAITL();
  __builtin_amdgcn_s_setprio(1);
  mfmaq<MODE, 0, 2>(acc, af, bfB);
  __builtin_amdgcn_s_setprio(0);
  GBAR();
  // ---- phase 2: read A rows [wr*128+64, +64); stage next B0+B1 (legal: B reads
  //      sealed by phase-1 end barrier); MFMA Q(4,2). A fully read after this.
#pragma unroll
  for (int i = 0; i < 4; ++i)
#pragma unroll
    for (int kk = 0; kk < 2; ++kk) af[i][kk] = ldsfrag(as_, wr * 8 + 4 + i, kk, rbase);
  stage_half(Bt, bs_, 0, ks, col0, wave, rdec, cdec);
  stage_half(Bt, bs_, 1, ks, col0, wave, rdec, cdec);
  GBAR(); GWAITL();
  __builtin_amdgcn_s_setprio(1);
  mfmaq<MODE, 4, 2>(acc, af, bfB);
  __builtin_amdgcn_s_setprio(0);
  GBAR();
  // ---- phase 3: stage next A0+A1 (A reads sealed by phase-2 end barrier);
  //      MFMA Q(4,0); vmcnt(8) -> next buffer's refill fully landed
  stage_half(A,  as_, 0, ks, row0, wave, rdec, cdec);
  stage_half(A,  as_, 1, ks, row0, wave, rdec, cdec);
  GBAR();
  __builtin_amdgcn_s_setprio(1);
  mfmaq<MODE, 4, 0>(acc, af, bfA);
  __builtin_amdgcn_s_setprio(0);
  asm volatile("s_waitcnt vmcnt(8)" ::: "memory");
  GBAR();
}

template <int MODE>
__global__ __launch_bounds__(512, 2) void gemm256_bt(
    const unsigned short* __restrict__ A,
    const unsigned short* __restrict__ Bt,
    unsigned short* __restrict__ obf, float* __restrict__ of32,
    const float* __restrict__ bias) {
  __shared__ __align__(16) unsigned short As[2][16384];
  __shared__ __align__(16) unsigned short Bs[2][16384];
  const int tid  = threadIdx.x;
  const int lane = tid & 63;
  const int wave = tid >> 6;
  const int quad = lane >> 4;
  const int c16  = lane & 15;
  const int wr = wave >> 2, wc = wave & 3;

  // T1: XCD-aware remap. linear wgid % 8 == XCD (m09); XCD k gets rows
  // 4k..4k+3 x cols 0..7 (bijective: 256 = 8 * 32).
  const int wg  = blockIdx.y * 8 + blockIdx.x;
  const int xcd = wg & 7;
  const int idx = wg >> 3;
  const int row0 = (xcd * 4 + (idx >> 3)) * 256;
  const int col0 = (idx & 7) * 256;

  // swizzled per-lane fragment base within a subtile-pair (elems)
  const int rbase = c16 * 32 + ((quad * 8) ^ ((c16 >> 3) << 4));

  // staging decode: chunk c = ld*512 + tid covers LDS elems c*8..c*8+7
  int rdec[2], cdec[2];
#pragma unroll
  for (int ld = 0; ld < 2; ++ld) {
    const int c = ld * 512 + tid;
    rdec[ld] = ((c >> 7) << 4) + ((c >> 2) & 15);
    cdec[ld] = (((c >> 6) & 1) << 5) + (((c & 3) << 3) ^ (((c >> 5) & 1) << 4));
  }

  f32x4 acc[8][4];
#pragma unroll
  for (int i = 0; i < 8; ++i)
#pragma unroll
    for (int j = 0; j < 4; ++j)
#pragma unroll
      for (int r = 0; r < 4; ++r) acc[i][j][r] = 0.0f;

  bhalf8 af[4][2], bfA[2][2], bfB[2][2];

  // prologue: stage K-tile 0 -> buf0, K-tile 1 -> buf1 (16 loads/thread)
  stage_half(Bt, Bs[0], 0, 0,  col0, wave, rdec, cdec);
  stage_half(Bt, Bs[0], 1, 0,  col0, wave, rdec, cdec);
  stage_half(A,  As[0], 0, 0,  row0, wave, rdec, cdec);
  stage_half(A,  As[0], 1, 0,  row0, wave, rdec, cdec);
  stage_half(Bt, Bs[1], 0, 64, col0, wave, rdec, cdec);
  stage_half(Bt, Bs[1], 1, 64, col0, wave, rdec, cdec);
  stage_half(A,  As[1], 0, 64, row0, wave, rdec, cdec);
  stage_half(A,  As[1], 1, 64, row0, wave, rdec, cdec);
  asm volatile("s_waitcnt vmcnt(8)" ::: "memory");  // K-tile 0 landed
  GBAR();

#pragma unroll 1
  for (int it = 0; it < 16; ++it) {
    const int kA  = it * 128;
    const int ksA = (kA + 128 > 1984) ? 1984 : kA + 128;  // clamp: tail re-reads
    const int ksB = (kA + 192 > 1984) ? 1984 : kA + 192;  // valid addrs, never read
    ktile256<MODE>(A, Bt, As[0], Bs[0], ksA, row0, col0, wave, wr, wc, rbase,
                   rdec, cdec, acc, af, bfA, bfB);
    ktile256<MODE>(A, Bt, As[1], Bs[1], ksB, row0, col0, wave, wr, wc, rbase,
                   rdec, cdec, acc, af, bfA, bfB);
  }

#pragma unroll
  for (int i = 0; i < 8; ++i)
#pragma unroll
    for (int j = 0; j < 4; ++j)
#pragma unroll
      for (int r = 0; r < 4; ++r) {
        float v = acc[i][j][r];
        if (MODE == 2) {
          int m = row0 + wr * 128 + i * 16 + quad * 4 + r;
          int n = col0 + wc * 64 + j * 16 + c16;
          of32[(size_t)m * 2048 + n] = v + bias[n];
        } else if (MODE == 0) {
          int m = row0 + wr * 128 + i * 16 + quad * 4 + r;
          int n = col0 + wc * 64 + j * 16 + c16;
          int b = m >> 11, s = m & 2047;
          int h = n >> 7,  d = n & 127;
          obf[(((size_t)(b * 16 + h)) * 2048 + s) * 128 + d] = f2bf(v);
        } else {
          int n = col0 + wc * 64 + j * 16 + quad * 4 + r;
          int m = row0 + wr * 128 + i * 16 + c16;
          int b = m >> 11, s = m & 2047;
          int h = n >> 7,  d = n & 127;
          obf[(((size_t)(b * 16 + h)) * 128 + d) * 2048 + s] = f2bf(v);
        }
      }
}

// ---------------- flash attention: S^T formulation ----------------
// Q,K: [b,h,s,128] bf16;  Vt: [b,h,128,s] bf16;  O: [b,s,h*128] bf16
// S^T = K*Q^T so softmax rows live per-lane; K staged with row-permutation rho
// so exp'd P values are directly the B-fragment of mfma for O^T = V^T * P^T.
// R4: T14 prefetch done RIGHT -- __forceinline__ FUNCTIONS (not lambdas; R2's
// lambda wasn't inlined, so ref-passed arrays went to scratch: 654 MB writes).
// Double K/V reg sets, 2-unrolled loop, prefetch t+1 under compute of t.
// T5 setprio around QK^T and PV MFMA clusters (m191: +4-7% attn).
#define LQK 136   // 128 + 8 pad (pad is load-bearing: bank-spreads frag reads)
#define LV   72   // 64 + 8 pad
__device__ __forceinline__ void fl_load(const unsigned short* __restrict__ Kbh,
                                        const unsigned short* __restrict__ Vbh,
                                        int t0, int tid,
                                        bhalf8 (&rk)[4], bhalf8 (&rv)[4]) {
#pragma unroll
  for (int i = 0; i < 4; i++) {
    int chunk = i * 256 + tid;
    int t = chunk >> 4, dc = (chunk & 15) << 3;               // K: [t][d]
    rk[i] = *reinterpret_cast<const bhalf8*>(Kbh + (size_t)(t0 + t) * 128 + dc);
    int d = chunk >> 3, tc = (chunk & 7) << 3;                // V^T: [d][t]
    rv[i] = *reinterpret_cast<const bhalf8*>(Vbh + (size_t)d * 2048 + t0 + tc);
  }
}

__device__ __forceinline__ void fl_tile(
    const unsigned short* __restrict__ Kbh, const unsigned short* __restrict__ Vbh,
    unsigned short* Ks, unsigned short* Vs,
    const bhalf8 (&qb)[4], f32x4 (&o_acc)[8], float& m_i, float& l_i,
    bhalf8 (&rk)[4], bhalf8 (&rv)[4], bhalf8 (&nk)[4], bhalf8 (&nv)[4],
    int it, int nt, int q0, int tid, int quad, int c16, int qidx) {
  const int t0 = it * 64;
  const float SL = ATTN_SCALE * LOG2E;
  __syncthreads();   // prior LDS reads done before overwrite
#pragma unroll
  for (int i = 0; i < 4; i++) {
    int chunk = i * 256 + tid;
    int t = chunk >> 4, dc = (chunk & 15) << 3;
    // rho(t): makes P land in B-frag order (k=8*quad+j)
    int row = (((t >> 5) << 1) | ((t >> 2) & 1)) * 16 + ((t >> 3) & 3) * 4 + (t & 3);
    *reinterpret_cast<bhalf8*>(Ks + row * LQK + dc) = rk[i];
    int d = chunk >> 3, tc = (chunk & 7) << 3;
    *reinterpret_cast<bhalf8*>(Vs + d * LV + tc) = rv[i];
  }
  __syncthreads();

  // T14: issue next tile's loads now; latency hides under QK^T+softmax+PV
  if (it + 1 < nt) fl_load(Kbh, Vbh, t0 + 64, tid, nk, nv);

  // QK^T: kk-outer so st[0..3] interleave (no back-to-back dependent MFMA)
  f32x4 st[4];
#pragma unroll
  for (int tt = 0; tt < 4; tt++)
#pragma unroll
    for (int r = 0; r < 4; r++) st[tt][r] = 0.0f;
  __builtin_amdgcn_s_setprio(1);
#pragma unroll
  for (int kk = 0; kk < 4; kk++)
#pragma unroll
    for (int tt = 0; tt < 4; tt++) {
      bhalf8 ka = *reinterpret_cast<const bhalf8*>(Ks + (tt * 16 + c16) * LQK + kk * 32 + quad * 8);
      st[tt] = __builtin_amdgcn_mfma_f32_16x16x32_bf16(ka, qb[kk], st[tt], 0, 0, 0);
    }
  __builtin_amdgcn_s_setprio(0);

  const bool diag = (t0 == q0);
  float pv[4][4];
  float rmax = -__builtin_inff();     // max over RAW scores (SL>0 commutes)
#pragma unroll
  for (int tt = 0; tt < 4; tt++)
#pragma unroll
    for (int r = 0; r < 4; r++) {
      float x = st[tt][r];
      if (diag) {
        int t = t0 + ((tt >> 1) << 5) + (quad << 3) + ((tt & 1) << 2) + r;
        if (t > qidx) x = -__builtin_inff();
      }
      pv[tt][r] = x;
      rmax = fmaxf(rmax, x);
    }
  rmax = fmaxf(rmax, __shfl_xor(rmax, 16));
  rmax = fmaxf(rmax, __shfl_xor(rmax, 32));
  const float pmax_s = rmax * SL;     // tile max in log2-scaled domain

  // T13 defer-max: only rescale when some row's max grew past threshold
  if (__any(pmax_s > m_i + 8.0f)) {
    const float mnew = fmaxf(m_i, pmax_s);
    const float alpha = exp2f(m_i - mnew);   // 0 when m_i=-inf
    m_i = mnew;
    l_i *= alpha;
#pragma unroll
    for (int jd = 0; jd < 8; jd++)
#pragma unroll
      for (int r = 0; r < 4; r++) o_acc[jd][r] *= alpha;
  }

  float rs = 0.0f;
#pragma unroll
  for (int tt = 0; tt < 4; tt++)
#pragma unroll
    for (int r = 0; r < 4; r++) {
      float p = exp2f(__builtin_fmaf(pv[tt][r], SL, -m_i));  // scale folded
      pv[tt][r] = p;
      rs += p;
    }
  l_i += rs;

  // O^T += V^T * P^T ; P^T B-frag packed in-register via v_perm
#pragma unroll
  for (int u = 0; u < 2; u++) {
    union { bhalf8 h; uint4 w; } pu;
    pu.w.x = pack_bf16_2(pv[2 * u][0],     pv[2 * u][1]);
    pu.w.y = pack_bf16_2(pv[2 * u][2],     pv[2 * u][3]);
    pu.w.z = pack_bf16_2(pv[2 * u + 1][0], pv[2 * u + 1][1]);
    pu.w.w = pack_bf16_2(pv[2 * u + 1][2], pv[2 * u + 1][3]);
    __builtin_amdgcn_s_setprio(1);
#pragma unroll
    for (int jd = 0; jd < 8; jd++) {
      bhalf8 va = *reinterpret_cast<const bhalf8*>(Vs + (jd * 16 + c16) * LV + u * 32 + quad * 8);
      o_acc[jd] = __builtin_amdgcn_mfma_f32_16x16x32_bf16(va, pu.h, o_acc[jd], 0, 0, 0);
    }
    __builtin_amdgcn_s_setprio(0);
  }
}

__global__ __launch_bounds__(256, 4) void flash_kernel(
    const unsigned short* __restrict__ Q,
    const unsigned short* __restrict__ K,
    const unsigned short* __restrict__ Vt,
    unsigned short* __restrict__ O) {
  const int tid  = threadIdx.x;
  const int lane = tid & 63;
  const int wave = tid >> 6;
  const int quad = lane >> 4;
  const int c16  = lane & 15;
  const int bh = blockIdx.x;                 // bh fast => heavy q-tiles spread first
  const int q0 = (31 - blockIdx.y) * 64;     // longest-first (causal tail fix)
  const int bb = bh >> 4, hh = bh & 15;
  const int qidx = q0 + wave * 16 + c16;

  __shared__ __align__(16) unsigned short Ks[64 * LQK];
  __shared__ __align__(16) unsigned short Vs[128 * LV];   // [d][t]

  const unsigned short* Kbh = K  + (size_t)bh * 2048 * 128;
  const unsigned short* Vbh = Vt + (size_t)bh * 128 * 2048;
  const int nt = q0 / 64 + 1;

  // K/V tile-0 loads issue first; latency hides under Q staging
  bhalf8 rkA[4], rvA[4], rkB[4], rvB[4];
  fl_load(Kbh, Vbh, 0, tid, rkA, rvA);

  // stage Q tile into Ks (overlay; Q frags read once), layout [t][d]
  const unsigned short* Qg = Q + ((size_t)bh * 2048 + q0) * 128;
#pragma unroll
  for (int i = 0; i < 4; i++) {
    int chunk = i * 256 + tid;
    int t = chunk >> 4, dc = (chunk & 15) << 3;
    *reinterpret_cast<bhalf8*>(Ks + t * LQK + dc) =
        *reinterpret_cast<const bhalf8*>(Qg + chunk * 8);
  }
  __syncthreads();
  bhalf8 qb[4];   // Q as B-operand: B[n=q=lane&15][k=quad*8+j]
#pragma unroll
  for (int kk = 0; kk < 4; kk++)
    qb[kk] = *reinterpret_cast<const bhalf8*>(Ks + (wave * 16 + c16) * LQK + kk * 32 + quad * 8);

  f32x4 o_acc[8];   // O^T: col q=c16, row d=jd*16+quad*4+r
#pragma unroll
  for (int jd = 0; jd < 8; jd++)
#pragma unroll
    for (int r = 0; r < 4; r++) o_acc[jd][r] = 0.0f;
  float m_i = -__builtin_inff(), l_i = 0.0f;

  int it = 0;
#pragma unroll 1
  for (;;) {
    fl_tile(Kbh, Vbh, Ks, Vs, qb, o_acc, m_i, l_i,
            rkA, rvA, rkB, rvB, it, nt, q0, tid, quad, c16, qidx);
    if (++it == nt) break;
    fl_tile(Kbh, Vbh, Ks, Vs, qb, o_acc, m_i, l_i,
            rkB, rvB, rkA, rvA, it, nt, q0, tid, quad, c16, qidx);
    if (++it == nt) break;
  }

  l_i += __shfl_xor(l_i, 16);
  l_i += __shfl_xor(l_i, 32);
  const float inv = 1.0f / l_i;
#pragma unroll
  for (int jd = 0; jd < 8; jd++) {
    unsigned lo = (unsigned)f2bf(o_acc[jd][0] * inv) | ((unsigned)f2bf(o_acc[jd][1] * inv) << 16);
    unsigned hi = (unsigned)f2bf(o_acc[jd][2] * inv) | ((unsigned)f2bf(o_acc[jd][3] * inv) << 16);
    *reinterpret_cast<uint2*>(O + ((size_t)(bb * 2048 + qidx)) * 2048 + hh * 128 + jd * 16 + quad * 4) =
        make_uint2(lo, hi);
  }
}

extern "C" void kernel_launch(void* const* d_in, const int* in_sizes, int n_in,
                              void* d_out, int out_size, void* d_ws, size_t ws_size,
                              hipStream_t stream) {
  const float* x  = (const float*)d_in[0];
  const float* wq = (const float*)d_in[1];
  const float* wk = (const float*)d_in[2];
  const float* wv = (const float*)d_in[3];
  const float* wp = (const float*)d_in[4];
  const float* bp = (const float*)d_in[5];
  float* out = (float*)d_out;

  unsigned short* ws  = (unsigned short*)d_ws;
  const size_t ME = (size_t)8192 * 2048;
  const size_t EE = (size_t)2048 * 2048;
  unsigned short* xb  = ws;
  unsigned short* wqb = xb  + ME;
  unsigned short* wkb = wqb + EE;
  unsigned short* wvb = wkb + EE;
  unsigned short* wpb = wvb + EE;
  unsigned short* Qb  = wpb + EE;          // [b,h,s,d]
  unsigned short* Kb  = Qb  + ME;          // [b,h,s,d]
  unsigned short* Vtb = Kb  + ME;          // [b,h,d,s]
  unsigned short* Ob  = Vtb + ME;          // [b,s,h*d]

  cvt_kernel<<<16384, 256, 0, stream>>>(x,  xb,  (int)(ME / 4));
  cvt_kernel<<<4096,  256, 0, stream>>>(wq, wqb, (int)(EE / 4));
  cvt_kernel<<<4096,  256, 0, stream>>>(wk, wkb, (int)(EE / 4));
  cvt_kernel<<<4096,  256, 0, stream>>>(wv, wvb, (int)(EE / 4));
  cvt_kernel<<<4096,  256, 0, stream>>>(wp, wpb, (int)(EE / 4));

  dim3 g2(8, 32);  // 2048/256 x 8192/256 = 256 blocks = 1/CU, no tail
  gemm256_bt<0><<<g2, 512, 0, stream>>>(xb, wqb, Qb,  nullptr, nullptr);
  gemm256_bt<0><<<g2, 512, 0, stream>>>(xb, wkb, Kb,  nullptr, nullptr);
  gemm256_bt<1><<<g2, 512, 0, stream>>>(xb, wvb, Vtb, nullptr, nullptr);

  flash_kernel<<<dim3(64, 32), 256, 0, stream>>>(Qb, Kb, Vtb, Ob);

  gemm256_bt<2><<<g2, 512, 0, stream>>>(Ob, wpb, nullptr, out, bp);
}

// Round 5
// 543.354 us; speedup vs baseline: 1.7966x; 1.7966x over previous
//
#include <hip/hip_runtime.h>

#define LOG2E 1.4426950408889634f
#define ATTN_SCALE 0.08838834764831843f   // 1/sqrt(128)

using bhalf8 = __attribute__((ext_vector_type(8))) short;  // 8 bf16 in 4 VGPRs
using f32x4  = __attribute__((ext_vector_type(4))) float;  // MFMA accumulator

// round-to-nearest-even fp32 -> bf16
__device__ __forceinline__ unsigned short f2bf(float f) {
  unsigned u = __float_as_uint(f);
  u += 0x7fffu + ((u >> 16) & 1u);
  return (unsigned short)(u >> 16);
}

// pack two fp32 -> bf16x2 (round-half-up) with one v_perm_b32
__device__ __forceinline__ unsigned pack_bf16_2(float lo, float hi) {
  unsigned a = __float_as_uint(lo) + 0x8000u;
  unsigned b = __float_as_uint(hi) + 0x8000u;
  return __builtin_amdgcn_perm(b, a, 0x07060302);  // D = {b.hi16, a.hi16}
}

// async global->LDS DMA, 16B per lane; lds dest must be wave-uniform base
__device__ __forceinline__ void gl_lds16(const unsigned short* g, unsigned short* l) {
  __builtin_amdgcn_global_load_lds(
      (const __attribute__((address_space(1))) void*)g,
      (__attribute__((address_space(3))) void*)l, 16, 0, 0);
}

// ---------------- fp32 -> bf16 convert, 4 elems/thread ----------------
__global__ void cvt_kernel(const float* __restrict__ src,
                           unsigned short* __restrict__ dst, int n4) {
  int i = blockIdx.x * blockDim.x + threadIdx.x;
  if (i >= n4) return;
  float4 f = reinterpret_cast<const float4*>(src)[i];
  unsigned lo = (unsigned)f2bf(f.x) | ((unsigned)f2bf(f.y) << 16);
  unsigned hi = (unsigned)f2bf(f.z) | ((unsigned)f2bf(f.w) << 16);
  reinterpret_cast<uint2*>(dst)[i] = make_uint2(lo, hi);
}

// =====================================================================
// 256x256-tile GEMM, C = A[M,2048] * Bt[N,2048]^T
// 512 threads (8 waves, 2Mx4N), BK=64, 128 KiB LDS double-buffer.
// R5 schedule: 2 barriers per K-tile (was 8). All frag ds_reads issue at the
// top; NO manual lgkmcnt(0) -- the compiler inserts minimal COUNTED lgkmcnt
// before each consuming MFMA (m97 asm evidence), so bfB/af-hi drains overlap
// Q00/Q02 MFMAs. Safety: every read's consumer precedes GBAR#1, so all reads
// are drained when staging DMA (into this same buffer, for K-tile t+2) is
// issued. vmcnt(8)+GBAR#2 seals tile t+1's DMAs CU-wide before its reads.
// T1 XCD remap. MFMA kk-outer (dependent acc writes spaced by 8).
// MODE 0: bf16 out, split heads [b,h,s,d]   (Q, K projections)
// MODE 1: bf16 out, transposed [b,h,d,s]    (V projection; MFMA swapped)
// MODE 2: fp32 out + bias, row-major [M,N]  (output projection)
// =====================================================================
#define GBAR()  asm volatile("s_barrier" ::: "memory")

__device__ __forceinline__ bhalf8 ldsfrag(const unsigned short* b, int rb, int kk,
                                          int rbase) {
  return *reinterpret_cast<const bhalf8*>(b + rb * 1024 + kk * 512 + rbase);
}

template <int MODE, int I0, int J0>
__device__ __forceinline__ void mfmaq(f32x4 (&acc)[8][4], const bhalf8 (&afr)[4][2],
                                      const bhalf8 (&bfr)[2][2]) {
#pragma unroll
  for (int kk = 0; kk < 2; ++kk)
#pragma unroll
    for (int i = 0; i < 4; ++i)
#pragma unroll
      for (int j = 0; j < 2; ++j) {
        if (MODE == 1)
          acc[I0 + i][J0 + j] = __builtin_amdgcn_mfma_f32_16x16x32_bf16(
              bfr[j][kk], afr[i][kk], acc[I0 + i][J0 + j], 0, 0, 0);
        else
          acc[I0 + i][J0 + j] = __builtin_amdgcn_mfma_f32_16x16x32_bf16(
              afr[i][kk], bfr[j][kk], acc[I0 + i][J0 + j], 0, 0, 0);
      }
}

// stage one half-tile (128 rows x 64 k) : 2 x global_load_lds per thread.
// rdec/cdec: per-thread (row, swizzled-k) decode of the linear LDS chunk.
__device__ __forceinline__ void stage_half(const unsigned short* __restrict__ M,
                                           unsigned short* dstbase, int h, int ks,
                                           int rowb, int wave, const int (&rdec)[2],
                                           const int (&cdec)[2]) {
#pragma unroll
  for (int ld = 0; ld < 2; ++ld)
    gl_lds16(M + (size_t)(rowb + rdec[ld] + h * 128) * 2048 + ks + cdec[ld],
             dstbase + h * 8192 + ld * 4096 + wave * 512);
}

template <int MODE>
__device__ __forceinline__ void ktile256(
    const unsigned short* __restrict__ A, const unsigned short* __restrict__ Bt,
    unsigned short* as_, unsigned short* bs_, int ks,
    int row0, int col0, int wave, int wr, int wc, int rbase,
    const int (&rdec)[2], const int (&cdec)[2],
    f32x4 (&acc)[8][4], bhalf8 (&af)[4][2], bhalf8 (&bfA)[2][2], bhalf8 (&bfB)[2][2]) {
  // ---- issue A-lo + all-B frag reads; compiler inserts counted lgkmcnt
#pragma unroll
  for (int i = 0; i < 4; ++i)
#pragma unroll
    for (int kk = 0; kk < 2; ++kk) af[i][kk] = ldsfrag(as_, wr * 8 + i, kk, rbase);
#pragma unroll
  for (int j = 0; j < 2; ++j)
#pragma unroll
    for (int kk = 0; kk < 2; ++kk) bfA[j][kk] = ldsfrag(bs_, wc * 4 + j, kk, rbase);
#pragma unroll
  for (int j = 0; j < 2; ++j)
#pragma unroll
    for (int kk = 0; kk < 2; ++kk) bfB[j][kk] = ldsfrag(bs_, wc * 4 + 2 + j, kk, rbase);

  __builtin_amdgcn_s_setprio(1);
  mfmaq<MODE, 0, 0>(acc, af, bfA);     // waits af-lo+bfA only (counted)
  mfmaq<MODE, 0, 2>(acc, af, bfB);     // bfB drained under Q00
  __builtin_amdgcn_s_setprio(0);

  // ---- A-hi frag reads (compiler interleaves issue with Q00/Q02 MFMAs)
#pragma unroll
  for (int i = 0; i < 4; ++i)
#pragma unroll
    for (int kk = 0; kk < 2; ++kk) af[i][kk] = ldsfrag(as_, wr * 8 + 4 + i, kk, rbase);
  __builtin_amdgcn_s_setprio(1);
  mfmaq<MODE, 4, 2>(acc, af, bfB);     // waits af-hi; last reads -> wave drained
  __builtin_amdgcn_s_setprio(0);

  GBAR();  // all waves drained ALL reads of this buffer -> overwrite is safe

  // ---- stage K-tile t+2 into this buffer (async DMA, lands >=1 tile later)
  stage_half(Bt, bs_, 0, ks, col0, wave, rdec, cdec);
  stage_half(Bt, bs_, 1, ks, col0, wave, rdec, cdec);
  stage_half(A,  as_, 0, ks, row0, wave, rdec, cdec);
  stage_half(A,  as_, 1, ks, row0, wave, rdec, cdec);

  __builtin_amdgcn_s_setprio(1);
  mfmaq<MODE, 4, 0>(acc, af, bfA);     // register-only operands
  __builtin_amdgcn_s_setprio(0);

  asm volatile("s_waitcnt vmcnt(8)" ::: "memory");  // t+1's 8 DMAs landed
  GBAR();  // ...landed for EVERY wave -> next tile may read other buffer
}

template <int MODE>
__global__ __launch_bounds__(512, 2) void gemm256_bt(
    const unsigned short* __restrict__ A,
    const unsigned short* __restrict__ Bt,
    unsigned short* __restrict__ obf, float* __restrict__ of32,
    const float* __restrict__ bias) {
  __shared__ __align__(16) unsigned short As[2][16384];
  __shared__ __align__(16) unsigned short Bs[2][16384];
  const int tid  = threadIdx.x;
  const int lane = tid & 63;
  const int wave = tid >> 6;
  const int quad = lane >> 4;
  const int c16  = lane & 15;
  const int wr = wave >> 2, wc = wave & 3;

  // T1: XCD-aware remap. linear wgid % 8 == XCD (m09); XCD k gets rows
  // 4k..4k+3 x cols 0..7 (bijective: 256 = 8 * 32).
  const int wg  = blockIdx.y * 8 + blockIdx.x;
  const int xcd = wg & 7;
  const int idx = wg >> 3;
  const int row0 = (xcd * 4 + (idx >> 3)) * 256;
  const int col0 = (idx & 7) * 256;

  // swizzled per-lane fragment base within a subtile-pair (elems)
  const int rbase = c16 * 32 + ((quad * 8) ^ ((c16 >> 3) << 4));

  // staging decode: chunk c = ld*512 + tid covers LDS elems c*8..c*8+7
  int rdec[2], cdec[2];
#pragma unroll
  for (int ld = 0; ld < 2; ++ld) {
    const int c = ld * 512 + tid;
    rdec[ld] = ((c >> 7) << 4) + ((c >> 2) & 15);
    cdec[ld] = (((c >> 6) & 1) << 5) + (((c & 3) << 3) ^ (((c >> 5) & 1) << 4));
  }

  f32x4 acc[8][4];
#pragma unroll
  for (int i = 0; i < 8; ++i)
#pragma unroll
    for (int j = 0; j < 4; ++j)
#pragma unroll
      for (int r = 0; r < 4; ++r) acc[i][j][r] = 0.0f;

  bhalf8 af[4][2], bfA[2][2], bfB[2][2];

  // prologue: stage K-tile 0 -> buf0, K-tile 1 -> buf1 (16 loads/thread)
  stage_half(Bt, Bs[0], 0, 0,  col0, wave, rdec, cdec);
  stage_half(Bt, Bs[0], 1, 0,  col0, wave, rdec, cdec);
  stage_half(A,  As[0], 0, 0,  row0, wave, rdec, cdec);
  stage_half(A,  As[0], 1, 0,  row0, wave, rdec, cdec);
  stage_half(Bt, Bs[1], 0, 64, col0, wave, rdec, cdec);
  stage_half(Bt, Bs[1], 1, 64, col0, wave, rdec, cdec);
  stage_half(A,  As[1], 0, 64, row0, wave, rdec, cdec);
  stage_half(A,  As[1], 1, 64, row0, wave, rdec, cdec);
  asm volatile("s_waitcnt vmcnt(8)" ::: "memory");  // K-tile 0 landed
  GBAR();

#pragma unroll 1
  for (int it = 0; it < 16; ++it) {
    const int kA  = it * 128;
    const int ksA = (kA + 128 > 1984) ? 1984 : kA + 128;  // clamp: tail re-reads
    const int ksB = (kA + 192 > 1984) ? 1984 : kA + 192;  // valid addrs, never read
    ktile256<MODE>(A, Bt, As[0], Bs[0], ksA, row0, col0, wave, wr, wc, rbase,
                   rdec, cdec, acc, af, bfA, bfB);
    ktile256<MODE>(A, Bt, As[1], Bs[1], ksB, row0, col0, wave, wr, wc, rbase,
                   rdec, cdec, acc, af, bfA, bfB);
  }

#pragma unroll
  for (int i = 0; i < 8; ++i)
#pragma unroll
    for (int j = 0; j < 4; ++j)
#pragma unroll
      for (int r = 0; r < 4; ++r) {
        float v = acc[i][j][r];
        if (MODE == 2) {
          int m = row0 + wr * 128 + i * 16 + quad * 4 + r;
          int n = col0 + wc * 64 + j * 16 + c16;
          of32[(size_t)m * 2048 + n] = v + bias[n];
        } else if (MODE == 0) {
          int m = row0 + wr * 128 + i * 16 + quad * 4 + r;
          int n = col0 + wc * 64 + j * 16 + c16;
          int b = m >> 11, s = m & 2047;
          int h = n >> 7,  d = n & 127;
          obf[(((size_t)(b * 16 + h)) * 2048 + s) * 128 + d] = f2bf(v);
        } else {
          int n = col0 + wc * 64 + j * 16 + quad * 4 + r;
          int m = row0 + wr * 128 + i * 16 + c16;
          int b = m >> 11, s = m & 2047;
          int h = n >> 7,  d = n & 127;
          obf[(((size_t)(b * 16 + h)) * 128 + d) * 2048 + s] = f2bf(v);
        }
      }
}

// ---------------- flash attention: S^T formulation (R3-proven, 138 us) ------
// Q,K: [b,h,s,128] bf16;  Vt: [b,h,128,s] bf16;  O: [b,s,h*128] bf16
// S^T = K*Q^T so softmax rows live per-lane; K staged with row-permutation rho
// so exp'd P values are directly the B-fragment of mfma for O^T = V^T * P^T.
// NOTE: register K/V double-buffering (T14) tried twice (R2 lambda, R4
// forceinline fns) -- both spill to scratch (~1 GB traffic): the extra 64
// VGPRs don't fit the launch_bounds(256,4) budget. Do not reattempt in-reg.
#define LQK 136   // 128 + 8 pad (pad is load-bearing: bank-spreads frag reads)
#define LV   72   // 64 + 8 pad
__global__ __launch_bounds__(256, 4) void flash_kernel(
    const unsigned short* __restrict__ Q,
    const unsigned short* __restrict__ K,
    const unsigned short* __restrict__ Vt,
    unsigned short* __restrict__ O) {
  const int tid  = threadIdx.x;
  const int lane = tid & 63;
  const int wave = tid >> 6;
  const int quad = lane >> 4;
  const int c16  = lane & 15;
  const int bh = blockIdx.x;                 // bh fast => heavy q-tiles spread first
  const int q0 = (31 - blockIdx.y) * 64;     // longest-first (causal tail fix)
  const int bb = bh >> 4, hh = bh & 15;
  const int qidx = q0 + wave * 16 + c16;
  const float SL = ATTN_SCALE * LOG2E;       // softmax in log2 domain

  __shared__ __align__(16) unsigned short Ks[64 * LQK];
  __shared__ __align__(16) unsigned short Vs[128 * LV];   // [d][t]

  // stage Q tile into Ks (overlay; Q frags read once), layout [t][d]
  const unsigned short* Qg = Q + ((size_t)bh * 2048 + q0) * 128;
#pragma unroll
  for (int i = 0; i < 4; i++) {
    int chunk = i * 256 + tid;
    int t = chunk >> 4, dc = (chunk & 15) << 3;
    *reinterpret_cast<bhalf8*>(Ks + t * LQK + dc) =
        *reinterpret_cast<const bhalf8*>(Qg + chunk * 8);
  }
  __syncthreads();
  bhalf8 qb[4];   // Q as B-operand: B[n=q=lane&15][k=quad*8+j]
#pragma unroll
  for (int kk = 0; kk < 4; kk++)
    qb[kk] = *reinterpret_cast<const bhalf8*>(Ks + (wave * 16 + c16) * LQK + kk * 32 + quad * 8);

  f32x4 o_acc[8];   // O^T: col q=c16, row d=jd*16+quad*4+r
#pragma unroll
  for (int jd = 0; jd < 8; jd++)
#pragma unroll
    for (int r = 0; r < 4; r++) o_acc[jd][r] = 0.0f;
  float m_i = -__builtin_inff(), l_i = 0.0f;

  const unsigned short* Kbh = K  + (size_t)bh * 2048 * 128;
  const unsigned short* Vbh = Vt + (size_t)bh * 128 * 2048;

  const int nt = q0 / 64 + 1;
  for (int it = 0; it < nt; ++it) {
    const int t0 = it * 64;
    bhalf8 rk[4], rv[4];
#pragma unroll
    for (int i = 0; i < 4; i++) {
      int chunk = i * 256 + tid;
      int t = chunk >> 4, dc = (chunk & 15) << 3;               // K: [t][d]
      rk[i] = *reinterpret_cast<const bhalf8*>(Kbh + (size_t)(t0 + t) * 128 + dc);
      int d = chunk >> 3, tc = (chunk & 7) << 3;                // V^T: [d][t]
      rv[i] = *reinterpret_cast<const bhalf8*>(Vbh + (size_t)d * 2048 + t0 + tc);
    }
    __syncthreads();
#pragma unroll
    for (int i = 0; i < 4; i++) {
      int chunk = i * 256 + tid;
      int t = chunk >> 4, dc = (chunk & 15) << 3;
      // rho(t): makes P land in B-frag order (k=8*quad+j)
      int row = (((t >> 5) << 1) | ((t >> 2) & 1)) * 16 + ((t >> 3) & 3) * 4 + (t & 3);
      *reinterpret_cast<bhalf8*>(Ks + row * LQK + dc) = rk[i];
      int d = chunk >> 3, tc = (chunk & 7) << 3;
      *reinterpret_cast<bhalf8*>(Vs + d * LV + tc) = rv[i];
    }
    __syncthreads();

    // QK^T: kk-outer so st[0..3] interleave (no back-to-back dependent MFMA)
    f32x4 st[4];
#pragma unroll
    for (int tt = 0; tt < 4; tt++)
#pragma unroll
      for (int r = 0; r < 4; r++) st[tt][r] = 0.0f;
#pragma unroll
    for (int kk = 0; kk < 4; kk++)
#pragma unroll
      for (int tt = 0; tt < 4; tt++) {
        bhalf8 ka = *reinterpret_cast<const bhalf8*>(Ks + (tt * 16 + c16) * LQK + kk * 32 + quad * 8);
        st[tt] = __builtin_amdgcn_mfma_f32_16x16x32_bf16(ka, qb[kk], st[tt], 0, 0, 0);
      }

    const bool diag = (t0 == q0);
    float pv[4][4];
    float rmax = -__builtin_inff();     // max over RAW scores (SL>0 commutes)
#pragma unroll
    for (int tt = 0; tt < 4; tt++)
#pragma unroll
      for (int r = 0; r < 4; r++) {
        float x = st[tt][r];
        if (diag) {
          int t = t0 + ((tt >> 1) << 5) + (quad << 3) + ((tt & 1) << 2) + r;
          if (t > qidx) x = -__builtin_inff();
        }
        pv[tt][r] = x;
        rmax = fmaxf(rmax, x);
      }
    rmax = fmaxf(rmax, __shfl_xor(rmax, 16));
    rmax = fmaxf(rmax, __shfl_xor(rmax, 32));
    const float pmax_s = rmax * SL;     // tile max in log2-scaled domain

    // T13 defer-max: only rescale when some row's max grew past threshold
    if (__any(pmax_s > m_i + 8.0f)) {
      const float mnew = fmaxf(m_i, pmax_s);
      const float alpha = exp2f(m_i - mnew);   // 0 when m_i=-inf
      m_i = mnew;
      l_i *= alpha;
#pragma unroll
      for (int jd = 0; jd < 8; jd++)
#pragma unroll
        for (int r = 0; r < 4; r++) o_acc[jd][r] *= alpha;
    }

    float rs = 0.0f;
#pragma unroll
    for (int tt = 0; tt < 4; tt++)
#pragma unroll
      for (int r = 0; r < 4; r++) {
        float p = exp2f(__builtin_fmaf(pv[tt][r], SL, -m_i));  // scale folded
        pv[tt][r] = p;
        rs += p;
      }
    l_i += rs;

    // O^T += V^T * P^T ; P^T B-frag packed in-register via v_perm
#pragma unroll
    for (int u = 0; u < 2; u++) {
      union { bhalf8 h; uint4 w; } pu;
      pu.w.x = pack_bf16_2(pv[2 * u][0],     pv[2 * u][1]);
      pu.w.y = pack_bf16_2(pv[2 * u][2],     pv[2 * u][3]);
      pu.w.z = pack_bf16_2(pv[2 * u + 1][0], pv[2 * u + 1][1]);
      pu.w.w = pack_bf16_2(pv[2 * u + 1][2], pv[2 * u + 1][3]);
#pragma unroll
      for (int jd = 0; jd < 8; jd++) {
        bhalf8 va = *reinterpret_cast<const bhalf8*>(Vs + (jd * 16 + c16) * LV + u * 32 + quad * 8);
        o_acc[jd] = __builtin_amdgcn_mfma_f32_16x16x32_bf16(va, pu.h, o_acc[jd], 0, 0, 0);
      }
    }
  }

  l_i += __shfl_xor(l_i, 16);
  l_i += __shfl_xor(l_i, 32);
  const float inv = 1.0f / l_i;
#pragma unroll
  for (int jd = 0; jd < 8; jd++) {
    unsigned lo = (unsigned)f2bf(o_acc[jd][0] * inv) | ((unsigned)f2bf(o_acc[jd][1] * inv) << 16);
    unsigned hi = (unsigned)f2bf(o_acc[jd][2] * inv) | ((unsigned)f2bf(o_acc[jd][3] * inv) << 16);
    *reinterpret_cast<uint2*>(O + ((size_t)(bb * 2048 + qidx)) * 2048 + hh * 128 + jd * 16 + quad * 4) =
        make_uint2(lo, hi);
  }
}

extern "C" void kernel_launch(void* const* d_in, const int* in_sizes, int n_in,
                              void* d_out, int out_size, void* d_ws, size_t ws_size,
                              hipStream_t stream) {
  const float* x  = (const float*)d_in[0];
  const float* wq = (const float*)d_in[1];
  const float* wk = (const float*)d_in[2];
  const float* wv = (const float*)d_in[3];
  const float* wp = (const float*)d_in[4];
  const float* bp = (const float*)d_in[5];
  float* out = (float*)d_out;

  unsigned short* ws  = (unsigned short*)d_ws;
  const size_t ME = (size_t)8192 * 2048;
  const size_t EE = (size_t)2048 * 2048;
  unsigned short* xb  = ws;
  unsigned short* wqb = xb  + ME;
  unsigned short* wkb = wqb + EE;
  unsigned short* wvb = wkb + EE;
  unsigned short* wpb = wvb + EE;
  unsigned short* Qb  = wpb + EE;          // [b,h,s,d]
  unsigned short* Kb  = Qb  + ME;          // [b,h,s,d]
  unsigned short* Vtb = Kb  + ME;          // [b,h,d,s]
  unsigned short* Ob  = Vtb + ME;          // [b,s,h*d]

  cvt_kernel<<<16384, 256, 0, stream>>>(x,  xb,  (int)(ME / 4));
  cvt_kernel<<<4096,  256, 0, stream>>>(wq, wqb, (int)(EE / 4));
  cvt_kernel<<<4096,  256, 0, stream>>>(wk, wkb, (int)(EE / 4));
  cvt_kernel<<<4096,  256, 0, stream>>>(wv, wvb, (int)(EE / 4));
  cvt_kernel<<<4096,  256, 0, stream>>>(wp, wpb, (int)(EE / 4));

  dim3 g2(8, 32);  // 2048/256 x 8192/256 = 256 blocks = 1/CU, no tail
  gemm256_bt<0><<<g2, 512, 0, stream>>>(xb, wqb, Qb,  nullptr, nullptr);
  gemm256_bt<0><<<g2, 512, 0, stream>>>(xb, wkb, Kb,  nullptr, nullptr);
  gemm256_bt<1><<<g2, 512, 0, stream>>>(xb, wvb, Vtb, nullptr, nullptr);

  flash_kernel<<<dim3(64, 32), 256, 0, stream>>>(Qb, Kb, Vtb, Ob);

  gemm256_bt<2><<<g2, 512, 0, stream>>>(Ob, wpb, nullptr, out, bp);
}